// Round 15
// baseline (452.610 us; speedup 1.0000x reference)
//
#include <hip/hip_runtime.h>

#define IMG 256
#define TSZ 64
#define TPB 64
#define TILES 4
#define NIMG 8
#define NTIL (TILES * TILES)
#define NBLK (NIMG * NTIL)

// ctrl layout (unsigned words), zeroed via hipMemsetAsync before each launch:
// [0..23] recon convergence tags tag[img][rc]; [24..31] per-image barrier
// counters; [32] any1; [33] any0; [34..41] CC per image; [42] done counter
#define CTRL_WORDS 64

// Swizzle: row r, col c -> r*64 + (c ^ (r&31)). Row walks and column walks
// both land <=2-way on the 32 banks (free on CDNA4 per m136).
__device__ __forceinline__ int swz(int r, int c) { return r * TSZ + (c ^ (r & 31)); }

__device__ __forceinline__ float agload(const float* p) {
  return __hip_atomic_load(p, __ATOMIC_RELAXED, __HIP_MEMORY_SCOPE_AGENT);
}
__device__ __forceinline__ void agstore(float* p, float v) {
  __hip_atomic_store(p, v, __ATOMIC_RELAXED, __HIP_MEMORY_SCOPE_AGENT);
}
__device__ __forceinline__ unsigned agloadu(const unsigned* p) {
  return __hip_atomic_load(p, __ATOMIC_RELAXED, __HIP_MEMORY_SCOPE_AGENT);
}

// 16-party per-image barrier: fence / arrive / spin / fence (r9-proven shape).
__device__ __forceinline__ void img_barrier(unsigned* bar, unsigned& gen, int tid) {
  __threadfence();
  __syncthreads();
  ++gen;
  if (tid == 0) {
    __hip_atomic_fetch_add(bar, 1u, __ATOMIC_RELAXED, __HIP_MEMORY_SCOPE_AGENT);
    while (__hip_atomic_load(bar, __ATOMIC_RELAXED, __HIP_MEMORY_SCOPE_AGENT) < (unsigned)NTIL * gen)
      __builtin_amdgcn_s_sleep(1);
  }
  __syncthreads();
  __threadfence();
}

// Geodesic reconstruction by dilation to exact fixpoint (r13-proven sweeps;
// chunk-of-16 register batches, #pragma unroll 1 on chunk loops — the proven
// codegen envelope). Coverage per iteration: H-fwd {W,N,S,NW,SW} + H-bwd
// {E,N,S,NE,SE} = all 8 neighbors (racy-but-monotone reads <= fixpoint), so a
// no-change iteration certifies the true fixpoint. V sweeps accelerate
// vertical propagation. TPB=64 = ONE WAVE: block vote is __any(chg), no LDS.
__device__ void recon(float* recS, float* maskS,
                      float* topH, float* botH, float* leftH, float* rightH,
                      float* rimg, unsigned* tag, unsigned* bar, unsigned& gen,
                      int R0, int C0, int tid) {
  const float NEGF = -__builtin_inff();
  for (unsigned it = 1;; ++it) {
    // ---- stage halos from published rec (fixed for this iteration) ----
    for (int i = tid; i < TSZ + 2; i += TPB) {
      int c = C0 + i - 1;
      int rT = R0 - 1, rB = R0 + TSZ;
      bool cok = (c >= 0 && c < IMG);
      topH[i] = (cok && rT >= 0)  ? agload(&rimg[rT * IMG + c]) : NEGF;
      botH[i] = (cok && rB < IMG) ? agload(&rimg[rB * IMG + c]) : NEGF;
    }
    for (int i = tid; i < TSZ; i += TPB) {
      int r = R0 + i;
      leftH[i]  = (C0 > 0)         ? agload(&rimg[r * IMG + C0 - 1])   : NEGF;
      rightH[i] = (C0 + TSZ < IMG) ? agload(&rimg[r * IMG + C0 + TSZ]) : NEGF;
    }
    __syncthreads();

    bool chg = false;
    // ======== H phase: lane owns row r = tid; chunk-of-16 buffered ======
    {
      const int r = tid;
      const int xs = r & 31;
      float* rowS = &recS[r * TSZ];
      const float* mrow = &maskS[r * TSZ];
      const float* upB = (r == 0)       ? &topH[1] : &recS[(r - 1) * TSZ];
      const int upX    = (r == 0)       ? 0        : ((r - 1) & 31);
      const float* dnB = (r == TSZ - 1) ? &botH[1] : &recS[(r + 1) * TSZ];
      const int dnX    = (r == TSZ - 1) ? 0        : ((r + 1) & 31);
      // forward: W(carry) + N,S + NW,SW (pu/pd = prev-column up/dn)
      {
        float carry = leftH[r];
        float pu = (r == 0)       ? topH[0] : leftH[r - 1];
        float pd = (r == TSZ - 1) ? botH[0] : leftH[r + 1];
#pragma unroll 1
        for (int k = 0; k < TSZ / 16; ++k) {
          const int c0 = k * 16;
          float o[16], mm[16], uu[16], dd[16];
#pragma unroll
          for (int i = 0; i < 16; ++i) {
            o[i]  = rowS[(c0 + i) ^ xs];
            mm[i] = mrow[(c0 + i) ^ xs];
            uu[i] = upB[(c0 + i) ^ upX];
            dd[i] = dnB[(c0 + i) ^ dnX];
          }
#pragma unroll
          for (int i = 0; i < 16; ++i) {
            float cand = fmaxf(fmaxf(fmaxf(uu[i], dd[i]), fmaxf(pu, pd)), carry);
            float v = fminf(mm[i], fmaxf(o[i], cand));
            chg |= (v > o[i]);
            o[i] = v; carry = v; pu = uu[i]; pd = dd[i];
          }
#pragma unroll
          for (int i = 0; i < 16; ++i) rowS[(c0 + i) ^ xs] = o[i];
        }
      }
      // backward: E(carry) + N,S + NE,SE
      {
        float carry = rightH[r];
        float pu = (r == 0)       ? topH[TSZ + 1] : rightH[r - 1];
        float pd = (r == TSZ - 1) ? botH[TSZ + 1] : rightH[r + 1];
#pragma unroll 1
        for (int k = TSZ / 16 - 1; k >= 0; --k) {
          const int c0 = k * 16;
          float o[16], mm[16], uu[16], dd[16];
#pragma unroll
          for (int i = 0; i < 16; ++i) {
            o[i]  = rowS[(c0 + i) ^ xs];
            mm[i] = mrow[(c0 + i) ^ xs];
            uu[i] = upB[(c0 + i) ^ upX];
            dd[i] = dnB[(c0 + i) ^ dnX];
          }
#pragma unroll
          for (int i = 15; i >= 0; --i) {
            float cand = fmaxf(fmaxf(fmaxf(uu[i], dd[i]), fmaxf(pu, pd)), carry);
            float v = fminf(mm[i], fmaxf(o[i], cand));
            chg |= (v > o[i]);
            o[i] = v; carry = v; pu = uu[i]; pd = dd[i];
          }
#pragma unroll
          for (int i = 0; i < 16; ++i) rowS[(c0 + i) ^ xs] = o[i];
        }
      }
    }
    __syncthreads();
    // ======== V phase: lane owns column c = tid; chunk-of-16 buffered ====
    {
      const int c = tid;
      // forward (top -> bottom): N via live carry
      {
        float carry = topH[c + 1];
#pragma unroll 1
        for (int k = 0; k < TSZ / 16; ++k) {
          const int r0i = k * 16;
          float o[16], mm[16];
#pragma unroll
          for (int i = 0; i < 16; ++i) {
            o[i]  = recS[swz(r0i + i, c)];
            mm[i] = maskS[swz(r0i + i, c)];
          }
#pragma unroll
          for (int i = 0; i < 16; ++i) {
            float v = fminf(mm[i], fmaxf(o[i], carry));
            chg |= (v > o[i]);
            o[i] = v; carry = v;
          }
#pragma unroll
          for (int i = 0; i < 16; ++i) recS[swz(r0i + i, c)] = o[i];
        }
      }
      // backward (bottom -> top): S via live carry
      {
        float carry = botH[c + 1];
#pragma unroll 1
        for (int k = TSZ / 16 - 1; k >= 0; --k) {
          const int r0i = k * 16;
          float o[16], mm[16];
#pragma unroll
          for (int i = 0; i < 16; ++i) {
            o[i]  = recS[swz(r0i + i, c)];
            mm[i] = maskS[swz(r0i + i, c)];
          }
#pragma unroll
          for (int i = 15; i >= 0; --i) {
            float v = fminf(mm[i], fmaxf(o[i], carry));
            chg |= (v > o[i]);
            o[i] = v; carry = v;
          }
#pragma unroll
          for (int i = 0; i < 16; ++i) recS[swz(r0i + i, c)] = o[i];
        }
      }
    }
    __syncthreads();

    // ---- single-wave vote (TPB=64): __any is block-uniform, no LDS ----
    bool blockChanged = __any(chg ? 1 : 0) != 0;
    if (blockChanged) {
      agstore(&rimg[R0 * IMG + C0 + tid],              recS[swz(0, tid)]);
      agstore(&rimg[(R0 + TSZ - 1) * IMG + C0 + tid],  recS[swz(TSZ - 1, tid)]);
      agstore(&rimg[(R0 + tid) * IMG + C0],            recS[swz(tid, 0)]);
      agstore(&rimg[(R0 + tid) * IMG + C0 + TSZ - 1],  recS[swz(tid, TSZ - 1)]);
      if (tid == 0) atomicMax(tag, it);
    }
    img_barrier(bar, gen, tid);
    if (agloadu(tag) < it) break;  // uniform within image: tag>=it only if change
  }
}

__global__ void __launch_bounds__(TPB)
hmax_kernel(const float* __restrict__ x, const float* __restrict__ hvec,
            const float* __restrict__ u, float* __restrict__ out,
            float* rec_g, unsigned* ctrl) {
  extern __shared__ float lds[];
  float* recS   = lds;
  float* maskS  = lds + TSZ * TSZ;
  float* topH   = lds + 2 * TSZ * TSZ;
  float* botH   = topH + (TSZ + 2);
  float* leftH  = botH + (TSZ + 2);
  float* rightH = leftH + TSZ;

  const int tid = threadIdx.x;
  const int blk = blockIdx.x;
  const int img = blk / NTIL;
  const int tin = blk % NTIL;
  const int ty = tin / TILES, tx = tin % TILES;
  const int R0 = ty * TSZ, C0 = tx * TSZ;
  const float* ximg = x + (size_t)img * IMG * IMG;
  const float* uimg = u + (size_t)img * IMG * IMG;
  float* rimg = rec_g + (size_t)img * IMG * IMG;
  unsigned* tag = &ctrl[img * 3];
  unsigned* bar = &ctrl[24 + img];
  unsigned gen = 0;

  // ---- init: mask = x, rec = x - h (LDS), publish ring ----
  const float hval = hvec[img];
  for (int rr = 0; rr < TSZ; ++rr) {
    float xv = ximg[(R0 + rr) * IMG + C0 + tid];
    maskS[swz(rr, tid)] = xv;
    recS[swz(rr, tid)] = xv - hval;
  }
  __syncthreads();
  agstore(&rimg[R0 * IMG + C0 + tid],              recS[swz(0, tid)]);
  agstore(&rimg[(R0 + TSZ - 1) * IMG + C0 + tid],  recS[swz(TSZ - 1, tid)]);
  agstore(&rimg[(R0 + tid) * IMG + C0],            recS[swz(tid, 0)]);
  agstore(&rimg[(R0 + tid) * IMG + C0 + TSZ - 1],  recS[swz(tid, TSZ - 1)]);
  img_barrier(bar, gen, tid);

  // ---- recon 1: xh = rho(x - h | x) ----
  recon(recS, maskS, topH, botH, leftH, rightH, rimg, &tag[0], bar, gen,
        R0, C0, tid);

  // ---- phase B: mask = xh, rec = xh - EPS, publish ring ----
  for (int rr = 0; rr < TSZ; ++rr) {
    int ix = swz(rr, tid);
    float xh = recS[ix];
    maskS[ix] = xh;
    recS[ix] = xh - 1e-05f;
  }
  __syncthreads();
  agstore(&rimg[R0 * IMG + C0 + tid],              recS[swz(0, tid)]);
  agstore(&rimg[(R0 + TSZ - 1) * IMG + C0 + tid],  recS[swz(TSZ - 1, tid)]);
  agstore(&rimg[(R0 + tid) * IMG + C0],            recS[swz(tid, 0)]);
  agstore(&rimg[(R0 + tid) * IMG + C0 + TSZ - 1],  recS[swz(tid, TSZ - 1)]);
  img_barrier(bar, gen, tid);

  // ---- recon 2: rho(xh - EPS | xh) ----
  recon(recS, maskS, topH, botH, leftH, rightH, rimg, &tag[1], bar, gen,
        R0, C0, tid);

  // ---- phase C: Rmax, marker = min(U, Rmax), publish ring ----
  bool a1 = false, a0 = false;
  for (int rr = 0; rr < TSZ; ++rr) {
    int ix = swz(rr, tid);
    float xh = maskS[ix];
    float r2 = recS[ix];
    float rm = (xh - r2 > 0.0f) ? 1.0f : 0.0f;
    a1 |= (rm == 1.0f);
    a0 |= (rm == 0.0f);
    float uv = uimg[(R0 + rr) * IMG + C0 + tid] / 100.0f;
    maskS[ix] = rm;
    recS[ix] = fminf(uv, rm);
  }
  if (__any(a1 ? 1 : 0) && tid == 0)
    __hip_atomic_fetch_or(&ctrl[32], 1u, __ATOMIC_RELAXED, __HIP_MEMORY_SCOPE_AGENT);
  if (__any(a0 ? 1 : 0) && tid == 0)
    __hip_atomic_fetch_or(&ctrl[33], 1u, __ATOMIC_RELAXED, __HIP_MEMORY_SCOPE_AGENT);
  __syncthreads();
  agstore(&rimg[R0 * IMG + C0 + tid],              recS[swz(0, tid)]);
  agstore(&rimg[(R0 + TSZ - 1) * IMG + C0 + tid],  recS[swz(TSZ - 1, tid)]);
  agstore(&rimg[(R0 + tid) * IMG + C0],            recS[swz(tid, 0)]);
  agstore(&rimg[(R0 + tid) * IMG + C0 + TSZ - 1],  recS[swz(tid, TSZ - 1)]);
  img_barrier(bar, gen, tid);

  // ---- recon 3: R = rho(min(U, Rmax) | Rmax) ----
  recon(recS, maskS, topH, botH, leftH, rightH, rimg, &tag[2], bar, gen,
        R0, C0, tid);

  // ---- phase D: count U == R per image ----
  unsigned cnt = 0;
  for (int rr = 0; rr < TSZ; ++rr) {
    float Rv = recS[swz(rr, tid)];
    float uv = uimg[(R0 + rr) * IMG + C0 + tid] / 100.0f;
    cnt += (uv == Rv) ? 1u : 0u;
  }
  for (int off = 32; off > 0; off >>= 1) cnt += __shfl_down(cnt, off, 64);
  if (tid == 0)
    __hip_atomic_fetch_add(&ctrl[34 + img], cnt, __ATOMIC_RELAXED, __HIP_MEMORY_SCOPE_AGENT);
  img_barrier(bar, gen, tid);  // all tiles' CC adds done

  if (tin == 0 && tid == 0)
    __hip_atomic_fetch_add(&ctrl[42], 1u, __ATOMIC_RELEASE, __HIP_MEMORY_SCOPE_AGENT);

  // ---- final join + output (block 0 only; co-resident via coop launch) ----
  if (blk == 0) {
    if (tid == 0) {
      while (__hip_atomic_load(&ctrl[42], __ATOMIC_RELAXED, __HIP_MEMORY_SCOPE_AGENT) < NIMG)
        __builtin_amdgcn_s_sleep(1);
    }
    __syncthreads();
    __threadfence();
    if (tid < NIMG) {
      float CC = (float)agloadu(&ctrl[34 + tid]);
      float gmax = agloadu(&ctrl[32]) ? 1.0f : 0.0f;
      float gmin = agloadu(&ctrl[33]) ? 0.0f : 1.0f;
      float d = gmax - gmin;
      out[tid] = fminf(CC, 100.0f * d * CC);
    }
  }
}

extern "C" void kernel_launch(void* const* d_in, const int* in_sizes, int n_in,
                              void* d_out, int out_size, void* d_ws, size_t ws_size,
                              hipStream_t stream) {
  const float* x = (const float*)d_in[0];
  const float* h = (const float*)d_in[1];
  const float* u = (const float*)d_in[2];
  float* out = (float*)d_out;
  float* rec_g = (float*)d_ws;
  unsigned* ctrl = (unsigned*)((char*)d_ws + (size_t)NIMG * IMG * IMG * sizeof(float));

  hipMemsetAsync(ctrl, 0, CTRL_WORDS * sizeof(unsigned), stream);

  const unsigned SH = (2 * TSZ * TSZ + 2 * (TSZ + 2) + 2 * TSZ) * sizeof(float);
  hipFuncSetAttribute((const void*)hmax_kernel,
                      hipFuncAttributeMaxDynamicSharedMemorySize, (int)SH);

  void* args[] = { (void*)&x, (void*)&h, (void*)&u, (void*)&out,
                   (void*)&rec_g, (void*)&ctrl };
  hipLaunchCooperativeKernel((void*)hmax_kernel, dim3(NBLK), dim3(TPB),
                             args, SH, stream);
}

// Round 16
// 396.478 us; speedup vs baseline: 1.1416x; 1.1416x over previous
//
#include <hip/hip_runtime.h>

#define IMG 256
#define TSZ 64
#define TPB 64
#define TILES 4
#define NIMG 8
#define NTIL (TILES * TILES)
#define NBLK (NIMG * NTIL)

// ctrl layout (unsigned words), zeroed via hipMemsetAsync before each launch:
// [0..23] recon convergence tags tag[img][rc]; [24..31] per-image barrier
// counters; [32] any1; [33] any0; [34..41] CC per image; [42] done counter
#define CTRL_WORDS 64

// Swizzle: row r, col c -> r*64 + (c ^ (r&31)). Row walks and column walks
// both land <=2-way on the 32 banks (free on CDNA4 per m136).
__device__ __forceinline__ int swz(int r, int c) { return r * TSZ + (c ^ (r & 31)); }

__device__ __forceinline__ float agload(const float* p) {
  return __hip_atomic_load(p, __ATOMIC_RELAXED, __HIP_MEMORY_SCOPE_AGENT);
}
__device__ __forceinline__ void agstore(float* p, float v) {
  __hip_atomic_store(p, v, __ATOMIC_RELAXED, __HIP_MEMORY_SCOPE_AGENT);
}
__device__ __forceinline__ unsigned agloadu(const unsigned* p) {
  return __hip_atomic_load(p, __ATOMIC_RELAXED, __HIP_MEMORY_SCOPE_AGENT);
}

// 16-party per-image barrier: fence / arrive / spin / fence (r9-proven shape).
__device__ __forceinline__ void img_barrier(unsigned* bar, unsigned& gen, int tid) {
  __threadfence();
  __syncthreads();
  ++gen;
  if (tid == 0) {
    __hip_atomic_fetch_add(bar, 1u, __ATOMIC_RELAXED, __HIP_MEMORY_SCOPE_AGENT);
    while (__hip_atomic_load(bar, __ATOMIC_RELAXED, __HIP_MEMORY_SCOPE_AGENT) < (unsigned)NTIL * gen)
      __builtin_amdgcn_s_sleep(1);
  }
  __syncthreads();
  __threadfence();
}

// Geodesic reconstruction by dilation to exact fixpoint (r13/r15-proven
// skeleton; chunk-of-16 register batches, #pragma unroll 1 on chunk loops —
// the proven codegen envelope). Coverage per iteration:
//   H-fwd {W,N,S,NW,SW} + H-bwd {E,N,S,NE,SE} = all 8 (certification basis)
//   V-fwd {N,W,E,NW,NE} + V-bwd {S,W,E,SW,SE}  (H-phase mirror; accelerator)
// All cross-lane/cross-tile reads racy-but-monotone (<= fixpoint), so a
// no-change iteration certifies the true fixpoint via the H coverage.
// TPB=64 = ONE WAVE: block vote is __any(chg), no LDS.
__device__ void recon(float* recS, float* maskS,
                      float* topH, float* botH, float* leftH, float* rightH,
                      float* rimg, unsigned* tag, unsigned* bar, unsigned& gen,
                      int R0, int C0, int tid) {
  const float NEGF = -__builtin_inff();
  for (unsigned it = 1;; ++it) {
    // ---- stage halos from published rec (fixed for this iteration) ----
    for (int i = tid; i < TSZ + 2; i += TPB) {
      int c = C0 + i - 1;
      int rT = R0 - 1, rB = R0 + TSZ;
      bool cok = (c >= 0 && c < IMG);
      topH[i] = (cok && rT >= 0)  ? agload(&rimg[rT * IMG + c]) : NEGF;
      botH[i] = (cok && rB < IMG) ? agload(&rimg[rB * IMG + c]) : NEGF;
    }
    for (int i = tid; i < TSZ; i += TPB) {
      int r = R0 + i;
      leftH[i]  = (C0 > 0)         ? agload(&rimg[r * IMG + C0 - 1])   : NEGF;
      rightH[i] = (C0 + TSZ < IMG) ? agload(&rimg[r * IMG + C0 + TSZ]) : NEGF;
    }
    __syncthreads();

    bool chg = false;
    // ======== H phase: lane owns row r = tid; chunk-of-16 buffered ======
    {
      const int r = tid;
      const int xs = r & 31;
      float* rowS = &recS[r * TSZ];
      const float* mrow = &maskS[r * TSZ];
      const float* upB = (r == 0)       ? &topH[1] : &recS[(r - 1) * TSZ];
      const int upX    = (r == 0)       ? 0        : ((r - 1) & 31);
      const float* dnB = (r == TSZ - 1) ? &botH[1] : &recS[(r + 1) * TSZ];
      const int dnX    = (r == TSZ - 1) ? 0        : ((r + 1) & 31);
      // forward: W(carry) + N,S + NW,SW (pu/pd = prev-column up/dn)
      {
        float carry = leftH[r];
        float pu = (r == 0)       ? topH[0] : leftH[r - 1];
        float pd = (r == TSZ - 1) ? botH[0] : leftH[r + 1];
#pragma unroll 1
        for (int k = 0; k < TSZ / 16; ++k) {
          const int c0 = k * 16;
          float o[16], mm[16], uu[16], dd[16];
#pragma unroll
          for (int i = 0; i < 16; ++i) {
            o[i]  = rowS[(c0 + i) ^ xs];
            mm[i] = mrow[(c0 + i) ^ xs];
            uu[i] = upB[(c0 + i) ^ upX];
            dd[i] = dnB[(c0 + i) ^ dnX];
          }
#pragma unroll
          for (int i = 0; i < 16; ++i) {
            float cand = fmaxf(fmaxf(fmaxf(uu[i], dd[i]), fmaxf(pu, pd)), carry);
            float v = fminf(mm[i], fmaxf(o[i], cand));
            chg |= (v > o[i]);
            o[i] = v; carry = v; pu = uu[i]; pd = dd[i];
          }
#pragma unroll
          for (int i = 0; i < 16; ++i) rowS[(c0 + i) ^ xs] = o[i];
        }
      }
      // backward: E(carry) + N,S + NE,SE
      {
        float carry = rightH[r];
        float pu = (r == 0)       ? topH[TSZ + 1] : rightH[r - 1];
        float pd = (r == TSZ - 1) ? botH[TSZ + 1] : rightH[r + 1];
#pragma unroll 1
        for (int k = TSZ / 16 - 1; k >= 0; --k) {
          const int c0 = k * 16;
          float o[16], mm[16], uu[16], dd[16];
#pragma unroll
          for (int i = 0; i < 16; ++i) {
            o[i]  = rowS[(c0 + i) ^ xs];
            mm[i] = mrow[(c0 + i) ^ xs];
            uu[i] = upB[(c0 + i) ^ upX];
            dd[i] = dnB[(c0 + i) ^ dnX];
          }
#pragma unroll
          for (int i = 15; i >= 0; --i) {
            float cand = fmaxf(fmaxf(fmaxf(uu[i], dd[i]), fmaxf(pu, pd)), carry);
            float v = fminf(mm[i], fmaxf(o[i], cand));
            chg |= (v > o[i]);
            o[i] = v; carry = v; pu = uu[i]; pd = dd[i];
          }
#pragma unroll
          for (int i = 0; i < 16; ++i) rowS[(c0 + i) ^ xs] = o[i];
        }
      }
    }
    __syncthreads();
    // ======== V phase: lane owns column c = tid; chunk-of-16 buffered,
    // with lateral W/E streams + sliding diagonals (H-phase mirror) ========
    {
      const int c = tid;
      const bool atL = (c == 0), atR = (c == TSZ - 1);
      // forward (top -> bottom): N(carry) + W,E + NW,NE
      {
        float carry = topH[c + 1];
        float pl = topH[c];        // NW of row 0
        float pr = topH[c + 2];    // NE of row 0
#pragma unroll 1
        for (int k = 0; k < TSZ / 16; ++k) {
          const int r0i = k * 16;
          float o[16], mm[16], ll[16], rr[16];
#pragma unroll
          for (int i = 0; i < 16; ++i) {
            int r = r0i + i;
            o[i]  = recS[swz(r, c)];
            mm[i] = maskS[swz(r, c)];
            ll[i] = atL ? leftH[r]  : recS[swz(r, c - 1)];
            rr[i] = atR ? rightH[r] : recS[swz(r, c + 1)];
          }
#pragma unroll
          for (int i = 0; i < 16; ++i) {
            float cand = fmaxf(fmaxf(fmaxf(ll[i], rr[i]), fmaxf(pl, pr)), carry);
            float v = fminf(mm[i], fmaxf(o[i], cand));
            chg |= (v > o[i]);
            o[i] = v; carry = v; pl = ll[i]; pr = rr[i];
          }
#pragma unroll
          for (int i = 0; i < 16; ++i) recS[swz(r0i + i, c)] = o[i];
        }
      }
      // backward (bottom -> top): S(carry) + W,E + SW,SE
      {
        float carry = botH[c + 1];
        float pl = botH[c];        // SW of row TSZ-1
        float pr = botH[c + 2];    // SE of row TSZ-1
#pragma unroll 1
        for (int k = TSZ / 16 - 1; k >= 0; --k) {
          const int r0i = k * 16;
          float o[16], mm[16], ll[16], rr[16];
#pragma unroll
          for (int i = 0; i < 16; ++i) {
            int r = r0i + i;
            o[i]  = recS[swz(r, c)];
            mm[i] = maskS[swz(r, c)];
            ll[i] = atL ? leftH[r]  : recS[swz(r, c - 1)];
            rr[i] = atR ? rightH[r] : recS[swz(r, c + 1)];
          }
#pragma unroll
          for (int i = 15; i >= 0; --i) {
            float cand = fmaxf(fmaxf(fmaxf(ll[i], rr[i]), fmaxf(pl, pr)), carry);
            float v = fminf(mm[i], fmaxf(o[i], cand));
            chg |= (v > o[i]);
            o[i] = v; carry = v; pl = ll[i]; pr = rr[i];
          }
#pragma unroll
          for (int i = 0; i < 16; ++i) recS[swz(r0i + i, c)] = o[i];
        }
      }
    }
    __syncthreads();

    // ---- single-wave vote (TPB=64): __any is block-uniform, no LDS ----
    bool blockChanged = __any(chg ? 1 : 0) != 0;
    if (blockChanged) {
      agstore(&rimg[R0 * IMG + C0 + tid],              recS[swz(0, tid)]);
      agstore(&rimg[(R0 + TSZ - 1) * IMG + C0 + tid],  recS[swz(TSZ - 1, tid)]);
      agstore(&rimg[(R0 + tid) * IMG + C0],            recS[swz(tid, 0)]);
      agstore(&rimg[(R0 + tid) * IMG + C0 + TSZ - 1],  recS[swz(tid, TSZ - 1)]);
      if (tid == 0) atomicMax(tag, it);
    }
    img_barrier(bar, gen, tid);
    if (agloadu(tag) < it) break;  // uniform within image: tag>=it only if change
  }
}

__global__ void __launch_bounds__(TPB)
hmax_kernel(const float* __restrict__ x, const float* __restrict__ hvec,
            const float* __restrict__ u, float* __restrict__ out,
            float* rec_g, unsigned* ctrl) {
  extern __shared__ float lds[];
  float* recS   = lds;
  float* maskS  = lds + TSZ * TSZ;
  float* topH   = lds + 2 * TSZ * TSZ;
  float* botH   = topH + (TSZ + 2);
  float* leftH  = botH + (TSZ + 2);
  float* rightH = leftH + TSZ;

  const int tid = threadIdx.x;
  const int blk = blockIdx.x;
  const int img = blk / NTIL;
  const int tin = blk % NTIL;
  const int ty = tin / TILES, tx = tin % TILES;
  const int R0 = ty * TSZ, C0 = tx * TSZ;
  const float* ximg = x + (size_t)img * IMG * IMG;
  const float* uimg = u + (size_t)img * IMG * IMG;
  float* rimg = rec_g + (size_t)img * IMG * IMG;
  unsigned* tag = &ctrl[img * 3];
  unsigned* bar = &ctrl[24 + img];
  unsigned gen = 0;

  // ---- init: mask = x, rec = x - h (LDS), publish ring ----
  const float hval = hvec[img];
  for (int rr = 0; rr < TSZ; ++rr) {
    float xv = ximg[(R0 + rr) * IMG + C0 + tid];
    maskS[swz(rr, tid)] = xv;
    recS[swz(rr, tid)] = xv - hval;
  }
  __syncthreads();
  agstore(&rimg[R0 * IMG + C0 + tid],              recS[swz(0, tid)]);
  agstore(&rimg[(R0 + TSZ - 1) * IMG + C0 + tid],  recS[swz(TSZ - 1, tid)]);
  agstore(&rimg[(R0 + tid) * IMG + C0],            recS[swz(tid, 0)]);
  agstore(&rimg[(R0 + tid) * IMG + C0 + TSZ - 1],  recS[swz(tid, TSZ - 1)]);
  img_barrier(bar, gen, tid);

  // ---- recon 1: xh = rho(x - h | x) ----
  recon(recS, maskS, topH, botH, leftH, rightH, rimg, &tag[0], bar, gen,
        R0, C0, tid);

  // ---- phase B: mask = xh, rec = xh - EPS, publish ring ----
  for (int rr = 0; rr < TSZ; ++rr) {
    int ix = swz(rr, tid);
    float xh = recS[ix];
    maskS[ix] = xh;
    recS[ix] = xh - 1e-05f;
  }
  __syncthreads();
  agstore(&rimg[R0 * IMG + C0 + tid],              recS[swz(0, tid)]);
  agstore(&rimg[(R0 + TSZ - 1) * IMG + C0 + tid],  recS[swz(TSZ - 1, tid)]);
  agstore(&rimg[(R0 + tid) * IMG + C0],            recS[swz(tid, 0)]);
  agstore(&rimg[(R0 + tid) * IMG + C0 + TSZ - 1],  recS[swz(tid, TSZ - 1)]);
  img_barrier(bar, gen, tid);

  // ---- recon 2: rho(xh - EPS | xh) ----
  recon(recS, maskS, topH, botH, leftH, rightH, rimg, &tag[1], bar, gen,
        R0, C0, tid);

  // ---- phase C: Rmax, marker = min(U, Rmax), publish ring ----
  bool a1 = false, a0 = false;
  for (int rr = 0; rr < TSZ; ++rr) {
    int ix = swz(rr, tid);
    float xh = maskS[ix];
    float r2 = recS[ix];
    float rm = (xh - r2 > 0.0f) ? 1.0f : 0.0f;
    a1 |= (rm == 1.0f);
    a0 |= (rm == 0.0f);
    float uv = uimg[(R0 + rr) * IMG + C0 + tid] / 100.0f;
    maskS[ix] = rm;
    recS[ix] = fminf(uv, rm);
  }
  if (__any(a1 ? 1 : 0) && tid == 0)
    __hip_atomic_fetch_or(&ctrl[32], 1u, __ATOMIC_RELAXED, __HIP_MEMORY_SCOPE_AGENT);
  if (__any(a0 ? 1 : 0) && tid == 0)
    __hip_atomic_fetch_or(&ctrl[33], 1u, __ATOMIC_RELAXED, __HIP_MEMORY_SCOPE_AGENT);
  __syncthreads();
  agstore(&rimg[R0 * IMG + C0 + tid],              recS[swz(0, tid)]);
  agstore(&rimg[(R0 + TSZ - 1) * IMG + C0 + tid],  recS[swz(TSZ - 1, tid)]);
  agstore(&rimg[(R0 + tid) * IMG + C0],            recS[swz(tid, 0)]);
  agstore(&rimg[(R0 + tid) * IMG + C0 + TSZ - 1],  recS[swz(tid, TSZ - 1)]);
  img_barrier(bar, gen, tid);

  // ---- recon 3: R = rho(min(U, Rmax) | Rmax) ----
  recon(recS, maskS, topH, botH, leftH, rightH, rimg, &tag[2], bar, gen,
        R0, C0, tid);

  // ---- phase D: count U == R per image ----
  unsigned cnt = 0;
  for (int rr = 0; rr < TSZ; ++rr) {
    float Rv = recS[swz(rr, tid)];
    float uv = uimg[(R0 + rr) * IMG + C0 + tid] / 100.0f;
    cnt += (uv == Rv) ? 1u : 0u;
  }
  for (int off = 32; off > 0; off >>= 1) cnt += __shfl_down(cnt, off, 64);
  if (tid == 0)
    __hip_atomic_fetch_add(&ctrl[34 + img], cnt, __ATOMIC_RELAXED, __HIP_MEMORY_SCOPE_AGENT);
  img_barrier(bar, gen, tid);  // all tiles' CC adds done

  if (tin == 0 && tid == 0)
    __hip_atomic_fetch_add(&ctrl[42], 1u, __ATOMIC_RELEASE, __HIP_MEMORY_SCOPE_AGENT);

  // ---- final join + output (block 0 only; co-resident via coop launch) ----
  if (blk == 0) {
    if (tid == 0) {
      while (__hip_atomic_load(&ctrl[42], __ATOMIC_RELAXED, __HIP_MEMORY_SCOPE_AGENT) < NIMG)
        __builtin_amdgcn_s_sleep(1);
    }
    __syncthreads();
    __threadfence();
    if (tid < NIMG) {
      float CC = (float)agloadu(&ctrl[34 + tid]);
      float gmax = agloadu(&ctrl[32]) ? 1.0f : 0.0f;
      float gmin = agloadu(&ctrl[33]) ? 0.0f : 1.0f;
      float d = gmax - gmin;
      out[tid] = fminf(CC, 100.0f * d * CC);
    }
  }
}

extern "C" void kernel_launch(void* const* d_in, const int* in_sizes, int n_in,
                              void* d_out, int out_size, void* d_ws, size_t ws_size,
                              hipStream_t stream) {
  const float* x = (const float*)d_in[0];
  const float* h = (const float*)d_in[1];
  const float* u = (const float*)d_in[2];
  float* out = (float*)d_out;
  float* rec_g = (float*)d_ws;
  unsigned* ctrl = (unsigned*)((char*)d_ws + (size_t)NIMG * IMG * IMG * sizeof(float));

  hipMemsetAsync(ctrl, 0, CTRL_WORDS * sizeof(unsigned), stream);

  const unsigned SH = (2 * TSZ * TSZ + 2 * (TSZ + 2) + 2 * TSZ) * sizeof(float);
  hipFuncSetAttribute((const void*)hmax_kernel,
                      hipFuncAttributeMaxDynamicSharedMemorySize, (int)SH);

  void* args[] = { (void*)&x, (void*)&h, (void*)&u, (void*)&out,
                   (void*)&rec_g, (void*)&ctrl };
  hipLaunchCooperativeKernel((void*)hmax_kernel, dim3(NBLK), dim3(TPB),
                             args, SH, stream);
}

// Round 17
// 374.546 us; speedup vs baseline: 1.2084x; 1.0586x over previous
//
#include <hip/hip_runtime.h>

#define IMG 256
#define TSZ 64
#define TPB 64
#define TILES 4
#define NIMG 8
#define NTIL (TILES * TILES)
#define NBLK (NIMG * NTIL)

// ctrl layout (unsigned words), zeroed via hipMemsetAsync before each launch:
// [0..23] recon convergence tags tag[img][rc]; [24..31] per-image barrier
// counters; [32] any1; [33] any0; [34..41] CC per image; [42] done counter
#define CTRL_WORDS 64

// Swizzle: row r, col c -> r*64 + (c ^ (r&31)). Row walks and column walks
// both land <=2-way on the 32 banks (free on CDNA4 per m136).
__device__ __forceinline__ int swz(int r, int c) { return r * TSZ + (c ^ (r & 31)); }

__device__ __forceinline__ float agload(const float* p) {
  return __hip_atomic_load(p, __ATOMIC_RELAXED, __HIP_MEMORY_SCOPE_AGENT);
}
__device__ __forceinline__ void agstore(float* p, float v) {
  __hip_atomic_store(p, v, __ATOMIC_RELAXED, __HIP_MEMORY_SCOPE_AGENT);
}
__device__ __forceinline__ unsigned agloadu(const unsigned* p) {
  return __hip_atomic_load(p, __ATOMIC_RELAXED, __HIP_MEMORY_SCOPE_AGENT);
}

// 16-party per-image barrier: fence / arrive / spin / fence (r9-proven shape).
__device__ __forceinline__ void img_barrier(unsigned* bar, unsigned& gen, int tid) {
  __threadfence();
  __syncthreads();
  ++gen;
  if (tid == 0) {
    __hip_atomic_fetch_add(bar, 1u, __ATOMIC_RELAXED, __HIP_MEMORY_SCOPE_AGENT);
    while (__hip_atomic_load(bar, __ATOMIC_RELAXED, __HIP_MEMORY_SCOPE_AGENT) < (unsigned)NTIL * gen)
      __builtin_amdgcn_s_sleep(1);
  }
  __syncthreads();
  __threadfence();
}

// Geodesic reconstruction by dilation to exact fixpoint (r16-proven sweeps;
// chunk-of-16 register batches, #pragma unroll 1 on chunk loops — the proven
// codegen envelope). Coverage per iteration:
//   H-fwd {W,N,S,NW,SW} + H-bwd {E,N,S,NE,SE} = all 8 (certification basis)
//   V-fwd {N,W,E,NW,NE} + V-bwd {S,W,E,SW,SE}  (H-phase mirror; accelerator)
// All cross-lane/cross-tile reads racy-but-monotone (<= fixpoint), so a
// no-change iteration certifies the true fixpoint via the H coverage.
// TPB=64 = ONE WAVE: block vote is __any(chg), no LDS.
__device__ void recon(float* recS, float* maskS,
                      float* topH, float* botH, float* leftH, float* rightH,
                      float* rimg, unsigned* tag, unsigned* bar, unsigned& gen,
                      int R0, int C0, int tid) {
  const float NEGF = -__builtin_inff();
  for (unsigned it = 1;; ++it) {
    // ---- stage halos from published rec (fixed for this iteration) ----
    for (int i = tid; i < TSZ + 2; i += TPB) {
      int c = C0 + i - 1;
      int rT = R0 - 1, rB = R0 + TSZ;
      bool cok = (c >= 0 && c < IMG);
      topH[i] = (cok && rT >= 0)  ? agload(&rimg[rT * IMG + c]) : NEGF;
      botH[i] = (cok && rB < IMG) ? agload(&rimg[rB * IMG + c]) : NEGF;
    }
    for (int i = tid; i < TSZ; i += TPB) {
      int r = R0 + i;
      leftH[i]  = (C0 > 0)         ? agload(&rimg[r * IMG + C0 - 1])   : NEGF;
      rightH[i] = (C0 + TSZ < IMG) ? agload(&rimg[r * IMG + C0 + TSZ]) : NEGF;
    }
    __syncthreads();

    bool chg = false;
    // ======== H phase: lane owns row r = tid; chunk-of-16 buffered ======
    {
      const int r = tid;
      const int xs = r & 31;
      float* rowS = &recS[r * TSZ];
      const float* mrow = &maskS[r * TSZ];
      const float* upB = (r == 0)       ? &topH[1] : &recS[(r - 1) * TSZ];
      const int upX    = (r == 0)       ? 0        : ((r - 1) & 31);
      const float* dnB = (r == TSZ - 1) ? &botH[1] : &recS[(r + 1) * TSZ];
      const int dnX    = (r == TSZ - 1) ? 0        : ((r + 1) & 31);
      // forward: W(carry) + N,S + NW,SW (pu/pd = prev-column up/dn)
      {
        float carry = leftH[r];
        float pu = (r == 0)       ? topH[0] : leftH[r - 1];
        float pd = (r == TSZ - 1) ? botH[0] : leftH[r + 1];
#pragma unroll 1
        for (int k = 0; k < TSZ / 16; ++k) {
          const int c0 = k * 16;
          float o[16], mm[16], uu[16], dd[16];
#pragma unroll
          for (int i = 0; i < 16; ++i) {
            o[i]  = rowS[(c0 + i) ^ xs];
            mm[i] = mrow[(c0 + i) ^ xs];
            uu[i] = upB[(c0 + i) ^ upX];
            dd[i] = dnB[(c0 + i) ^ dnX];
          }
#pragma unroll
          for (int i = 0; i < 16; ++i) {
            float cand = fmaxf(fmaxf(fmaxf(uu[i], dd[i]), fmaxf(pu, pd)), carry);
            float v = fminf(mm[i], fmaxf(o[i], cand));
            chg |= (v > o[i]);
            o[i] = v; carry = v; pu = uu[i]; pd = dd[i];
          }
#pragma unroll
          for (int i = 0; i < 16; ++i) rowS[(c0 + i) ^ xs] = o[i];
        }
      }
      // backward: E(carry) + N,S + NE,SE
      {
        float carry = rightH[r];
        float pu = (r == 0)       ? topH[TSZ + 1] : rightH[r - 1];
        float pd = (r == TSZ - 1) ? botH[TSZ + 1] : rightH[r + 1];
#pragma unroll 1
        for (int k = TSZ / 16 - 1; k >= 0; --k) {
          const int c0 = k * 16;
          float o[16], mm[16], uu[16], dd[16];
#pragma unroll
          for (int i = 0; i < 16; ++i) {
            o[i]  = rowS[(c0 + i) ^ xs];
            mm[i] = mrow[(c0 + i) ^ xs];
            uu[i] = upB[(c0 + i) ^ upX];
            dd[i] = dnB[(c0 + i) ^ dnX];
          }
#pragma unroll
          for (int i = 15; i >= 0; --i) {
            float cand = fmaxf(fmaxf(fmaxf(uu[i], dd[i]), fmaxf(pu, pd)), carry);
            float v = fminf(mm[i], fmaxf(o[i], cand));
            chg |= (v > o[i]);
            o[i] = v; carry = v; pu = uu[i]; pd = dd[i];
          }
#pragma unroll
          for (int i = 0; i < 16; ++i) rowS[(c0 + i) ^ xs] = o[i];
        }
      }
    }
    __syncthreads();
    // ======== V phase: lane owns column c = tid; chunk-of-16 buffered,
    // with lateral W/E streams + sliding diagonals (H-phase mirror) ========
    {
      const int c = tid;
      const bool atL = (c == 0), atR = (c == TSZ - 1);
      // forward (top -> bottom): N(carry) + W,E + NW,NE
      {
        float carry = topH[c + 1];
        float pl = topH[c];        // NW of row 0
        float pr = topH[c + 2];    // NE of row 0
#pragma unroll 1
        for (int k = 0; k < TSZ / 16; ++k) {
          const int r0i = k * 16;
          float o[16], mm[16], ll[16], rr[16];
#pragma unroll
          for (int i = 0; i < 16; ++i) {
            int r = r0i + i;
            o[i]  = recS[swz(r, c)];
            mm[i] = maskS[swz(r, c)];
            ll[i] = atL ? leftH[r]  : recS[swz(r, c - 1)];
            rr[i] = atR ? rightH[r] : recS[swz(r, c + 1)];
          }
#pragma unroll
          for (int i = 0; i < 16; ++i) {
            float cand = fmaxf(fmaxf(fmaxf(ll[i], rr[i]), fmaxf(pl, pr)), carry);
            float v = fminf(mm[i], fmaxf(o[i], cand));
            chg |= (v > o[i]);
            o[i] = v; carry = v; pl = ll[i]; pr = rr[i];
          }
#pragma unroll
          for (int i = 0; i < 16; ++i) recS[swz(r0i + i, c)] = o[i];
        }
      }
      // backward (bottom -> top): S(carry) + W,E + SW,SE
      {
        float carry = botH[c + 1];
        float pl = botH[c];        // SW of row TSZ-1
        float pr = botH[c + 2];    // SE of row TSZ-1
#pragma unroll 1
        for (int k = TSZ / 16 - 1; k >= 0; --k) {
          const int r0i = k * 16;
          float o[16], mm[16], ll[16], rr[16];
#pragma unroll
          for (int i = 0; i < 16; ++i) {
            int r = r0i + i;
            o[i]  = recS[swz(r, c)];
            mm[i] = maskS[swz(r, c)];
            ll[i] = atL ? leftH[r]  : recS[swz(r, c - 1)];
            rr[i] = atR ? rightH[r] : recS[swz(r, c + 1)];
          }
#pragma unroll
          for (int i = 15; i >= 0; --i) {
            float cand = fmaxf(fmaxf(fmaxf(ll[i], rr[i]), fmaxf(pl, pr)), carry);
            float v = fminf(mm[i], fmaxf(o[i], cand));
            chg |= (v > o[i]);
            o[i] = v; carry = v; pl = ll[i]; pr = rr[i];
          }
#pragma unroll
          for (int i = 0; i < 16; ++i) recS[swz(r0i + i, c)] = o[i];
        }
      }
    }
    __syncthreads();

    // ---- single-wave vote (TPB=64): __any is block-uniform, no LDS ----
    bool blockChanged = __any(chg ? 1 : 0) != 0;
    if (blockChanged) {
      agstore(&rimg[R0 * IMG + C0 + tid],              recS[swz(0, tid)]);
      agstore(&rimg[(R0 + TSZ - 1) * IMG + C0 + tid],  recS[swz(TSZ - 1, tid)]);
      agstore(&rimg[(R0 + tid) * IMG + C0],            recS[swz(tid, 0)]);
      agstore(&rimg[(R0 + tid) * IMG + C0 + TSZ - 1],  recS[swz(tid, TSZ - 1)]);
      if (tid == 0) atomicMax(tag, it);
    }
    img_barrier(bar, gen, tid);
    if (agloadu(tag) < it) break;  // uniform within image: tag>=it only if change
  }
}

__global__ void __launch_bounds__(TPB)
hmax_kernel(const float* __restrict__ x, const float* __restrict__ hvec,
            const float* __restrict__ u, float* __restrict__ out,
            float* rec_g, unsigned* ctrl) {
  extern __shared__ float lds[];
  float* recS   = lds;
  float* maskS  = lds + TSZ * TSZ;
  float* topH   = lds + 2 * TSZ * TSZ;
  float* botH   = topH + (TSZ + 2);
  float* leftH  = botH + (TSZ + 2);
  float* rightH = leftH + TSZ;

  const int tid = threadIdx.x;
  const int blk = blockIdx.x;
  // XCD-locality swizzle: round-robin dispatch puts blk%8 on XCD blk%8, so
  // img = blk % NIMG co-locates all 16 tiles of an image on one XCD — the
  // barrier counter, tags, and ring mailboxes become XCD-local L2 traffic.
  // Mapping affects speed only, never correctness (device-scope atomics).
  const int img = blk % NIMG;
  const int tin = blk / NIMG;
  const int ty = tin / TILES, tx = tin % TILES;
  const int R0 = ty * TSZ, C0 = tx * TSZ;
  const float* ximg = x + (size_t)img * IMG * IMG;
  const float* uimg = u + (size_t)img * IMG * IMG;
  float* rimg = rec_g + (size_t)img * IMG * IMG;
  unsigned* tag = &ctrl[img * 3];
  unsigned* bar = &ctrl[24 + img];
  unsigned gen = 0;

  // ---- init: mask = x, rec = x - h (LDS), publish ring ----
  const float hval = hvec[img];
  for (int rr = 0; rr < TSZ; ++rr) {
    float xv = ximg[(R0 + rr) * IMG + C0 + tid];
    maskS[swz(rr, tid)] = xv;
    recS[swz(rr, tid)] = xv - hval;
  }
  __syncthreads();
  agstore(&rimg[R0 * IMG + C0 + tid],              recS[swz(0, tid)]);
  agstore(&rimg[(R0 + TSZ - 1) * IMG + C0 + tid],  recS[swz(TSZ - 1, tid)]);
  agstore(&rimg[(R0 + tid) * IMG + C0],            recS[swz(tid, 0)]);
  agstore(&rimg[(R0 + tid) * IMG + C0 + TSZ - 1],  recS[swz(tid, TSZ - 1)]);
  img_barrier(bar, gen, tid);

  // ---- recon 1: xh = rho(x - h | x) ----
  recon(recS, maskS, topH, botH, leftH, rightH, rimg, &tag[0], bar, gen,
        R0, C0, tid);

  // ---- phase B: mask = xh, rec = xh - EPS, publish ring ----
  for (int rr = 0; rr < TSZ; ++rr) {
    int ix = swz(rr, tid);
    float xh = recS[ix];
    maskS[ix] = xh;
    recS[ix] = xh - 1e-05f;
  }
  __syncthreads();
  agstore(&rimg[R0 * IMG + C0 + tid],              recS[swz(0, tid)]);
  agstore(&rimg[(R0 + TSZ - 1) * IMG + C0 + tid],  recS[swz(TSZ - 1, tid)]);
  agstore(&rimg[(R0 + tid) * IMG + C0],            recS[swz(tid, 0)]);
  agstore(&rimg[(R0 + tid) * IMG + C0 + TSZ - 1],  recS[swz(tid, TSZ - 1)]);
  img_barrier(bar, gen, tid);

  // ---- recon 2: rho(xh - EPS | xh) ----
  recon(recS, maskS, topH, botH, leftH, rightH, rimg, &tag[1], bar, gen,
        R0, C0, tid);

  // ---- phase C: Rmax, marker = min(U, Rmax), publish ring ----
  bool a1 = false, a0 = false;
  for (int rr = 0; rr < TSZ; ++rr) {
    int ix = swz(rr, tid);
    float xh = maskS[ix];
    float r2 = recS[ix];
    float rm = (xh - r2 > 0.0f) ? 1.0f : 0.0f;
    a1 |= (rm == 1.0f);
    a0 |= (rm == 0.0f);
    float uv = uimg[(R0 + rr) * IMG + C0 + tid] / 100.0f;
    maskS[ix] = rm;
    recS[ix] = fminf(uv, rm);
  }
  if (__any(a1 ? 1 : 0) && tid == 0)
    __hip_atomic_fetch_or(&ctrl[32], 1u, __ATOMIC_RELAXED, __HIP_MEMORY_SCOPE_AGENT);
  if (__any(a0 ? 1 : 0) && tid == 0)
    __hip_atomic_fetch_or(&ctrl[33], 1u, __ATOMIC_RELAXED, __HIP_MEMORY_SCOPE_AGENT);
  __syncthreads();
  agstore(&rimg[R0 * IMG + C0 + tid],              recS[swz(0, tid)]);
  agstore(&rimg[(R0 + TSZ - 1) * IMG + C0 + tid],  recS[swz(TSZ - 1, tid)]);
  agstore(&rimg[(R0 + tid) * IMG + C0],            recS[swz(tid, 0)]);
  agstore(&rimg[(R0 + tid) * IMG + C0 + TSZ - 1],  recS[swz(tid, TSZ - 1)]);
  img_barrier(bar, gen, tid);

  // ---- recon 3: R = rho(min(U, Rmax) | Rmax) ----
  recon(recS, maskS, topH, botH, leftH, rightH, rimg, &tag[2], bar, gen,
        R0, C0, tid);

  // ---- phase D: count U == R per image ----
  unsigned cnt = 0;
  for (int rr = 0; rr < TSZ; ++rr) {
    float Rv = recS[swz(rr, tid)];
    float uv = uimg[(R0 + rr) * IMG + C0 + tid] / 100.0f;
    cnt += (uv == Rv) ? 1u : 0u;
  }
  for (int off = 32; off > 0; off >>= 1) cnt += __shfl_down(cnt, off, 64);
  if (tid == 0)
    __hip_atomic_fetch_add(&ctrl[34 + img], cnt, __ATOMIC_RELAXED, __HIP_MEMORY_SCOPE_AGENT);
  img_barrier(bar, gen, tid);  // all tiles' CC adds done

  if (tin == 0 && tid == 0)
    __hip_atomic_fetch_add(&ctrl[42], 1u, __ATOMIC_RELEASE, __HIP_MEMORY_SCOPE_AGENT);

  // ---- final join + output (block 0 only; co-resident via coop launch) ----
  if (blk == 0) {
    if (tid == 0) {
      while (__hip_atomic_load(&ctrl[42], __ATOMIC_RELAXED, __HIP_MEMORY_SCOPE_AGENT) < NIMG)
        __builtin_amdgcn_s_sleep(1);
    }
    __syncthreads();
    __threadfence();
    if (tid < NIMG) {
      float CC = (float)agloadu(&ctrl[34 + tid]);
      float gmax = agloadu(&ctrl[32]) ? 1.0f : 0.0f;
      float gmin = agloadu(&ctrl[33]) ? 0.0f : 1.0f;
      float d = gmax - gmin;
      out[tid] = fminf(CC, 100.0f * d * CC);
    }
  }
}

extern "C" void kernel_launch(void* const* d_in, const int* in_sizes, int n_in,
                              void* d_out, int out_size, void* d_ws, size_t ws_size,
                              hipStream_t stream) {
  const float* x = (const float*)d_in[0];
  const float* h = (const float*)d_in[1];
  const float* u = (const float*)d_in[2];
  float* out = (float*)d_out;
  float* rec_g = (float*)d_ws;
  unsigned* ctrl = (unsigned*)((char*)d_ws + (size_t)NIMG * IMG * IMG * sizeof(float));

  hipMemsetAsync(ctrl, 0, CTRL_WORDS * sizeof(unsigned), stream);

  const unsigned SH = (2 * TSZ * TSZ + 2 * (TSZ + 2) + 2 * TSZ) * sizeof(float);
  hipFuncSetAttribute((const void*)hmax_kernel,
                      hipFuncAttributeMaxDynamicSharedMemorySize, (int)SH);

  void* args[] = { (void*)&x, (void*)&h, (void*)&u, (void*)&out,
                   (void*)&rec_g, (void*)&ctrl };
  hipLaunchCooperativeKernel((void*)hmax_kernel, dim3(NBLK), dim3(TPB),
                             args, SH, stream);
}